// Round 1
// baseline (248.229 us; speedup 1.0000x reference)
//
#include <hip/hip_runtime.h>

// S4-style long conv: out[b,d,l] = sum_k kern[d,k] * x[b,d,l-k] + D[d]*x[b,d,l]
// kern[d,k] = exp(-dt_d*k)*cos(freq_d*k) / (sum_k' |...| + 1e-8), dt_d = exp(log_dt_d) >= 1.
// Taps beyond k=64 are < 1e-28 relative -> exact in f32 with K_TAPS=64 (FFT reference
// itself has ~1e-6 relative rounding). Memory-bound short-FIR formulation.

#define D_MODEL_C 256
#define LEN       8192
#define K_TAPS    64
#define TILE      2048
#define CPT       8                        // consecutive outputs per thread
#define NTHREADS  256
#define NF4       ((TILE + K_TAPS) / 4)    // 528 float4 units staged per block

// XOR-swizzle 16B units so the stride-2-f4 window reads hit all 8 bank groups.
__device__ __forceinline__ int swz(int f4idx) {
  return f4idx ^ ((f4idx >> 3) & 1);
}

__global__ __launch_bounds__(NTHREADS)
void s4_conv_kernel(const float* __restrict__ x,
                    const float* __restrict__ log_dt,
                    const float* __restrict__ freq,
                    const float* __restrict__ Dv,
                    float* __restrict__ out) {
  __shared__ float4 xs4[NF4];
  __shared__ float  wtap[K_TAPS];

  const int tid        = threadIdx.x;
  const int row        = blockIdx.y;            // b * D_MODEL + d
  const int d          = row & (D_MODEL_C - 1);
  const int tile_start = blockIdx.x * TILE;
  const float* xr      = x + (long long)row * LEN;

  // --- per-channel taps, computed by wave 0 (exactly 64 lanes) ---
  if (tid < K_TAPS) {
    const float dt = expf(log_dt[d]);
    const float kk = (float)tid;
    const float w  = expf(-dt * kk) * cosf(freq[d] * kk);
    float a = fabsf(w);
    #pragma unroll
    for (int off = 32; off >= 1; off >>= 1) a += __shfl_xor(a, off, 64);
    wtap[tid] = w / (a + 1e-8f);
  }

  // --- stage x tile + left halo (zeros before row start), swizzled ---
  for (int q4 = tid; q4 < NF4; q4 += NTHREADS) {
    const int g = tile_start - K_TAPS + q4 * 4;   // multiple of 4; g<0 => whole f4 OOB
    float4 v = make_float4(0.f, 0.f, 0.f, 0.f);
    if (g >= 0) v = *reinterpret_cast<const float4*>(xr + g);
    xs4[swz(q4)] = v;
  }
  __syncthreads();

  // --- pull this thread's 72-float window into registers (static indices) ---
  float w[CPT + K_TAPS];                  // w[q] = x[tile_start - K_TAPS + tid*CPT + q]
  const int basef4 = tid * (CPT / 4);     // 2*tid
  #pragma unroll
  for (int q = 0; q < (CPT + K_TAPS) / 4; ++q) {  // 18 x float4
    const float4 v = xs4[swz(basef4 + q)];
    w[q * 4 + 0] = v.x; w[q * 4 + 1] = v.y;
    w[q * 4 + 2] = v.z; w[q * 4 + 3] = v.w;
  }

  float acc[CPT];
  const float Dd = Dv[d];
  #pragma unroll
  for (int j = 0; j < CPT; ++j) acc[j] = Dd * w[K_TAPS + j];   // skip connection

  #pragma unroll
  for (int k = 0; k < K_TAPS; ++k) {
    const float wk = wtap[k];             // LDS broadcast, conflict-free
    #pragma unroll
    for (int j = 0; j < CPT; ++j)
      acc[j] = fmaf(wk, w[K_TAPS + j - k], acc[j]);
  }

  float* orow = out + (long long)row * LEN + tile_start + tid * CPT;
  *reinterpret_cast<float4*>(orow)     = make_float4(acc[0], acc[1], acc[2], acc[3]);
  *reinterpret_cast<float4*>(orow + 4) = make_float4(acc[4], acc[5], acc[6], acc[7]);
}

extern "C" void kernel_launch(void* const* d_in, const int* in_sizes, int n_in,
                              void* d_out, int out_size, void* d_ws, size_t ws_size,
                              hipStream_t stream) {
  const float* x      = (const float*)d_in[0];
  const float* log_dt = (const float*)d_in[1];
  const float* freq   = (const float*)d_in[2];
  const float* Dv     = (const float*)d_in[3];
  float* out          = (float*)d_out;

  const int rows = in_sizes[0] / LEN;     // B * D_MODEL = 4096
  dim3 grid(LEN / TILE, rows);            // (4, 4096)
  s4_conv_kernel<<<grid, NTHREADS, 0, stream>>>(x, log_dt, freq, Dv, out);
}